// Round 1
// baseline (731.926 us; speedup 1.0000x reference)
//
#include <hip/hip_runtime.h>

#define NUM_C 1000
#define COLS4 250      // 1000 floats / 4 per float4
#define GAMMA 0.9f

// --- 1. histogram of labels -------------------------------------------------
__global__ void count_kernel(const int* __restrict__ labels,
                             int* __restrict__ counts, int n) {
    int i = blockIdx.x * blockDim.x + threadIdx.x;
    int stride = gridDim.x * blockDim.x;
    for (; i < n; i += stride) {
        atomicAdd(&counts[labels[i]], 1);
    }
}

// --- 2. exclusive prefix sum over 1000 counts (single block) ---------------
__global__ void scan_kernel(const int* __restrict__ counts,
                            int* __restrict__ offsets) {
    __shared__ int s[1024];
    int tid = threadIdx.x;
    int v = (tid < NUM_C) ? counts[tid] : 0;
    s[tid] = v;
    __syncthreads();
    for (int d = 1; d < 1024; d <<= 1) {
        int x = (tid >= d) ? s[tid - d] : 0;
        __syncthreads();
        s[tid] += x;
        __syncthreads();
    }
    if (tid < NUM_C) offsets[tid] = s[tid] - v;   // exclusive
}

// --- 3. scatter row indices into class buckets ------------------------------
__global__ void scatter_kernel(const int* __restrict__ labels,
                               const int* __restrict__ offsets,
                               int* __restrict__ cursors,
                               int* __restrict__ rowidx, int n) {
    int i = blockIdx.x * blockDim.x + threadIdx.x;
    int stride = gridDim.x * blockDim.x;
    for (; i < n; i += stride) {
        int l = labels[i];
        int pos = offsets[l] + atomicAdd(&cursors[l], 1);
        rowidx[pos] = i;
    }
}

// --- 4. per-class column accumulation + EMA ---------------------------------
// grid (NUM_C, 2), block 128.  blockIdx.y selects column half (125 float4 each).
__global__ __launch_bounds__(128) void accum_kernel(
        const float* __restrict__ preds, const float* __restrict__ val,
        const int* __restrict__ counts, const int* __restrict__ offsets,
        const int* __restrict__ rowidx, float* __restrict__ out) {
    const int c    = blockIdx.x;
    const int tid  = threadIdx.x;                 // 0..127
    const int col4 = blockIdx.y * 125 + tid;      // float4 column index
    const bool active = (tid < 125);

    const float4* __restrict__ pv = (const float4*)preds;
    const float4* __restrict__ vv = (const float4*)val;
    float4* __restrict__ ov = (float4*)out;
    const size_t crow = (size_t)c * COLS4;

    const int nc  = counts[c];
    const int off = offsets[c];

    if (nc == 0) {            // empty class: passthrough val_preds
        if (active) ov[crow + col4] = vv[crow + col4];
        return;
    }

    __shared__ int rows_s[1024];
    float4 acc = {0.f, 0.f, 0.f, 0.f};

    for (int base = 0; base < nc; base += 1024) {
        int m = min(nc - base, 1024);
        for (int j = tid; j < m; j += 128) rows_s[j] = rowidx[off + base + j];
        __syncthreads();

        int r = 0;
        for (; r + 4 <= m; r += 4) {
            size_t i0 = (size_t)rows_s[r + 0] * COLS4;
            size_t i1 = (size_t)rows_s[r + 1] * COLS4;
            size_t i2 = (size_t)rows_s[r + 2] * COLS4;
            size_t i3 = (size_t)rows_s[r + 3] * COLS4;
            if (active) {
                float4 v0 = pv[i0 + col4];
                float4 v1 = pv[i1 + col4];
                float4 v2 = pv[i2 + col4];
                float4 v3 = pv[i3 + col4];
                acc.x += (v0.x + v1.x) + (v2.x + v3.x);
                acc.y += (v0.y + v1.y) + (v2.y + v3.y);
                acc.z += (v0.z + v1.z) + (v2.z + v3.z);
                acc.w += (v0.w + v1.w) + (v2.w + v3.w);
            }
        }
        for (; r < m; r++) {
            size_t i0 = (size_t)rows_s[r] * COLS4;
            if (active) {
                float4 v0 = pv[i0 + col4];
                acc.x += v0.x; acc.y += v0.y; acc.z += v0.z; acc.w += v0.w;
            }
        }
        __syncthreads();
    }

    if (active) {
        float inv = 1.0f / (float)nc;
        float4 vp = vv[crow + col4];
        float4 o;
        o.x = (1.0f - GAMMA) * (acc.x * inv) + GAMMA * vp.x;
        o.y = (1.0f - GAMMA) * (acc.y * inv) + GAMMA * vp.y;
        o.z = (1.0f - GAMMA) * (acc.z * inv) + GAMMA * vp.z;
        o.w = (1.0f - GAMMA) * (acc.w * inv) + GAMMA * vp.w;
        ov[crow + col4] = o;
    }
}

extern "C" void kernel_launch(void* const* d_in, const int* in_sizes, int n_in,
                              void* d_out, int out_size, void* d_ws, size_t ws_size,
                              hipStream_t stream) {
    const float* preds  = (const float*)d_in[0];
    const int*   labels = (const int*)d_in[1];
    const float* val    = (const float*)d_in[2];
    float*       out    = (float*)d_out;
    const int n = in_sizes[1];   // 131072 rows

    // workspace layout: counts[1024] | offsets[1024] | cursors[1024] | rowidx[n]
    char* ws = (char*)d_ws;
    int* counts  = (int*)(ws + 0);
    int* offsets = (int*)(ws + 4096);
    int* cursors = (int*)(ws + 8192);
    int* rowidx  = (int*)(ws + 12288);

    hipMemsetAsync(d_ws, 0, 12288, stream);  // zero counts + offsets + cursors
    count_kernel<<<256, 256, 0, stream>>>(labels, counts, n);
    scan_kernel<<<1, 1024, 0, stream>>>(counts, offsets);
    scatter_kernel<<<256, 256, 0, stream>>>(labels, offsets, cursors, rowidx, n);
    accum_kernel<<<dim3(NUM_C, 2), 128, 0, stream>>>(preds, val, counts, offsets,
                                                     rowidx, out);
}

// Round 3
// 706.586 us; speedup vs baseline: 1.0359x; 1.0359x over previous
//
#include <hip/hip_runtime.h>

#define NUM_C 1000
#define COLS4 250      // 1000 floats / 4 per float4
#define GAMMA 0.9f

typedef float v4f __attribute__((ext_vector_type(4)));   // clang-native vec4

// --- 1. histogram of labels -------------------------------------------------
__global__ void count_kernel(const int* __restrict__ labels,
                             int* __restrict__ counts, int n) {
    int i = blockIdx.x * blockDim.x + threadIdx.x;
    if (i < n) atomicAdd(&counts[labels[i]], 1);
}

// --- 2. exclusive prefix sum over 1000 counts (single block) ---------------
__global__ void scan_kernel(const int* __restrict__ counts,
                            int* __restrict__ offsets) {
    __shared__ int s[1024];
    int tid = threadIdx.x;
    int v = (tid < NUM_C) ? counts[tid] : 0;
    s[tid] = v;
    __syncthreads();
    for (int d = 1; d < 1024; d <<= 1) {
        int x = (tid >= d) ? s[tid - d] : 0;
        __syncthreads();
        s[tid] += x;
        __syncthreads();
    }
    if (tid < NUM_C) offsets[tid] = s[tid] - v;   // exclusive
}

// --- 3. scatter row indices into class buckets ------------------------------
__global__ void scatter_kernel(const int* __restrict__ labels,
                               const int* __restrict__ offsets,
                               int* __restrict__ cursors,
                               int* __restrict__ rowidx, int n) {
    int i = blockIdx.x * blockDim.x + threadIdx.x;
    if (i < n) {
        int l = labels[i];
        int pos = offsets[l] + atomicAdd(&cursors[l], 1);
        rowidx[pos] = i;
    }
}

// --- 4. per-class column accumulation + EMA ---------------------------------
// grid NUM_C, block 256 (250 active float4 lanes = one full 4 KB row/iter).
__global__ __launch_bounds__(256) void accum_kernel(
        const float* __restrict__ preds, const float* __restrict__ val,
        const int* __restrict__ counts, const int* __restrict__ offsets,
        const int* __restrict__ rowidx, float* __restrict__ out) {
    const int c   = blockIdx.x;
    const int tid = threadIdx.x;
    const bool active = (tid < COLS4);
    const int col4 = active ? tid : 0;   // clamp inactive lanes to a safe column

    const v4f* __restrict__ pv = (const v4f*)preds;
    const v4f* __restrict__ vv = (const v4f*)val;
    v4f* __restrict__ ov = (v4f*)out;
    const size_t crow = (size_t)c * COLS4;

    const int nc  = counts[c];
    const int off = offsets[c];

    if (nc == 0) {            // empty class: passthrough val_preds
        if (active) ov[crow + col4] = vv[crow + col4];
        return;
    }

    __shared__ int rows_s[512];
    v4f acc0 = {0.f, 0.f, 0.f, 0.f};
    v4f acc1 = {0.f, 0.f, 0.f, 0.f};

    for (int base = 0; base < nc; base += 512) {
        int m = min(nc - base, 512);
        if (tid < m) rows_s[tid] = rowidx[off + base + tid];
        if (tid + 256 < m) rows_s[tid + 256] = rowidx[off + base + tid + 256];
        __syncthreads();

        int r = 0;
        for (; r + 8 <= m; r += 8) {
            size_t i0 = (size_t)rows_s[r + 0] * COLS4 + col4;
            size_t i1 = (size_t)rows_s[r + 1] * COLS4 + col4;
            size_t i2 = (size_t)rows_s[r + 2] * COLS4 + col4;
            size_t i3 = (size_t)rows_s[r + 3] * COLS4 + col4;
            size_t i4 = (size_t)rows_s[r + 4] * COLS4 + col4;
            size_t i5 = (size_t)rows_s[r + 5] * COLS4 + col4;
            size_t i6 = (size_t)rows_s[r + 6] * COLS4 + col4;
            size_t i7 = (size_t)rows_s[r + 7] * COLS4 + col4;
            v4f v0 = __builtin_nontemporal_load(&pv[i0]);
            v4f v1 = __builtin_nontemporal_load(&pv[i1]);
            v4f v2 = __builtin_nontemporal_load(&pv[i2]);
            v4f v3 = __builtin_nontemporal_load(&pv[i3]);
            v4f v4 = __builtin_nontemporal_load(&pv[i4]);
            v4f v5 = __builtin_nontemporal_load(&pv[i5]);
            v4f v6 = __builtin_nontemporal_load(&pv[i6]);
            v4f v7 = __builtin_nontemporal_load(&pv[i7]);
            acc0 += (v0 + v1) + (v2 + v3);
            acc1 += (v4 + v5) + (v6 + v7);
        }
        for (; r < m; r++) {
            size_t i0 = (size_t)rows_s[r] * COLS4 + col4;
            acc0 += __builtin_nontemporal_load(&pv[i0]);
        }
        __syncthreads();
    }

    if (active) {
        float inv = 1.0f / (float)nc;
        v4f s = acc0 + acc1;
        v4f vp = vv[crow + col4];
        v4f o = (1.0f - GAMMA) * (s * inv) + GAMMA * vp;
        ov[crow + col4] = o;
    }
}

extern "C" void kernel_launch(void* const* d_in, const int* in_sizes, int n_in,
                              void* d_out, int out_size, void* d_ws, size_t ws_size,
                              hipStream_t stream) {
    const float* preds  = (const float*)d_in[0];
    const int*   labels = (const int*)d_in[1];
    const float* val    = (const float*)d_in[2];
    float*       out    = (float*)d_out;
    const int n = in_sizes[1];   // 131072 rows

    // workspace layout: counts[1024] | offsets[1024] | cursors[1024] | rowidx[n]
    char* ws = (char*)d_ws;
    int* counts  = (int*)(ws + 0);
    int* offsets = (int*)(ws + 4096);
    int* cursors = (int*)(ws + 8192);
    int* rowidx  = (int*)(ws + 12288);

    (void)hipMemsetAsync(d_ws, 0, 12288, stream);  // zero counts+offsets+cursors
    count_kernel<<<(n + 255) / 256, 256, 0, stream>>>(labels, counts, n);
    scan_kernel<<<1, 1024, 0, stream>>>(counts, offsets);
    scatter_kernel<<<(n + 255) / 256, 256, 0, stream>>>(labels, offsets, cursors, rowidx, n);
    accum_kernel<<<NUM_C, 256, 0, stream>>>(preds, val, counts, offsets, rowidx, out);
}